// Round 1
// baseline (530.451 us; speedup 1.0000x reference)
//
#include <hip/hip_runtime.h>

// Problem constants (derived from reference):
//   B=8, H=W=256, I_DIM=64, K_DIM=64 (hd_k=32), V_DIM=32 (hd_v=16), O_DIM=64
//   NH=2 heads, unfold: p=7, stride=21, dilation=4, npw=12 -> S=144 patches
//   Sampled grid: 84x84 positions per image; each sampled pixel in exactly ONE patch.
#define BB 8
#define HH 256
#define CIN 64
#define NPW 12
#define SPP 144
#define PP 49
#define PDIM 7
#define STRIDE 21
#define DIL 4
#define NS 84
#define HDK 32
#define HDV 16

// ---------------------------------------------------------------------------
// Kernel 1: one block per (b, patch). Gather x1/x2 pixels, project to
// K1/K2/V1/V2 (both heads), 49x49 dual softmax attention, scatter o1/o2 into
// dense OS[b][64][84][84] (gathered sampled-grid layout) in workspace.
// ---------------------------------------------------------------------------
__global__ __launch_bounds__(256) void k1_fused(
    const float* __restrict__ x1, const float* __restrict__ x2,
    const float* __restrict__ Wk, const float* __restrict__ bk,
    const float* __restrict__ Wv, const float* __restrict__ bv,
    float* __restrict__ OS)
{
  // kv rows: 0..63 = K1 (ch c -> head c/32, d=c%32), 64..127 = K2,
  //          128..159 = V1, 160..191 = V2
  __shared__ float kv[192][50];
  __shared__ union UU {
    float xs[2][CIN][50];                    // inputs (phase 0/1 only)
    struct { float A1[49][50]; float A2[49][50]; } a;  // attention (phase 2+)
  } u;
  __shared__ float rmax[49], rsum[49], cmax[49], csum[49];

  const int tid = threadIdx.x;
  const int blk = blockIdx.x;
  const int b  = blk / SPP;
  const int s  = blk % SPP;
  const int pi = s / NPW, pj = s % NPW;
  const int h0 = pi * STRIDE, w0 = pj * STRIDE;

  // ---- phase 0: gather x tiles into LDS ----
  for (int i = tid; i < 2 * CIN * PP; i += 256) {
    int src = i / (CIN * PP);
    int r = i - src * CIN * PP;
    int c = r / PP, t = r - c * PP;
    int ph = t / PDIM, pw = t - ph * PDIM;
    const float* xp = src ? x2 : x1;
    u.xs[src][c][t] =
        xp[(((size_t)b * CIN + c) * HH + (h0 + ph * DIL)) * HH + (w0 + pw * DIL)];
  }
  __syncthreads();

  // ---- phase 1: projections (192 rows x 49 px), 4 rows x 4 px register tile
  for (int task = tid; task < 48 * 13; task += 256) {
    int g = task / 13, tg = task % 13;
    int row0 = g * 4;
    int t0 = tg * 4;
    int tc[4];
    #pragma unroll
    for (int j = 0; j < 4; j++) tc[j] = min(t0 + j, PP - 1);
    int src = (row0 < 64) ? 0 : (row0 < 128 ? 1 : (row0 < 160 ? 0 : 1));
    const float* wbase;
    float bias[4];
    if (row0 < 128) {
      wbase = Wk + row0 * 64;
      #pragma unroll
      for (int j = 0; j < 4; j++) bias[j] = bk[row0 + j];
    } else {
      wbase = Wv + (row0 - 128) * 64;
      #pragma unroll
      for (int j = 0; j < 4; j++) bias[j] = bv[row0 - 128 + j];
    }
    const float* xsrc = &u.xs[src][0][0];
    float acc[4][4];
    #pragma unroll
    for (int i = 0; i < 4; i++)
      #pragma unroll
      for (int j = 0; j < 4; j++) acc[i][j] = 0.f;
    for (int c = 0; c < 64; c++) {
      float wv0 = wbase[c];
      float wv1 = wbase[64 + c];
      float wv2 = wbase[128 + c];
      float wv3 = wbase[192 + c];
      #pragma unroll
      for (int j = 0; j < 4; j++) {
        float xv = xsrc[c * 50 + tc[j]];
        acc[0][j] += wv0 * xv;
        acc[1][j] += wv1 * xv;
        acc[2][j] += wv2 * xv;
        acc[3][j] += wv3 * xv;
      }
    }
    #pragma unroll
    for (int i = 0; i < 4; i++)
      #pragma unroll
      for (int j = 0; j < 4; j++)
        if (t0 + j < PP) kv[row0 + i][t0 + j] = acc[i][j] + bias[i];
  }
  __syncthreads();  // xs dead from here; union reused for A1/A2

  const float scale = 0.17677669529663687f;  // 1/sqrt(32)

  for (int n = 0; n < 2; n++) {
    // ---- kk[x][y] = scale * sum_d K1[n*32+d][x] * K2[n*32+d][y], 4x4 tiles
    for (int task = tid; task < 13 * 13; task += 256) {
      int xg = task / 13, yg = task % 13;
      int x0 = xg * 4, y0 = yg * 4;
      int xc[4], yc[4];
      #pragma unroll
      for (int j = 0; j < 4; j++) { xc[j] = min(x0 + j, 48); yc[j] = min(y0 + j, 48); }
      float acc[4][4];
      #pragma unroll
      for (int i = 0; i < 4; i++)
        #pragma unroll
        for (int j = 0; j < 4; j++) acc[i][j] = 0.f;
      for (int d = 0; d < HDK; d++) {
        const float* k1r = kv[n * HDK + d];
        const float* k2r = kv[64 + n * HDK + d];
        float a0 = k1r[xc[0]], a1v = k1r[xc[1]], a2v = k1r[xc[2]], a3v = k1r[xc[3]];
        float b0 = k2r[yc[0]], b1v = k2r[yc[1]], b2v = k2r[yc[2]], b3v = k2r[yc[3]];
        acc[0][0] += a0 * b0;  acc[0][1] += a0 * b1v;  acc[0][2] += a0 * b2v;  acc[0][3] += a0 * b3v;
        acc[1][0] += a1v * b0; acc[1][1] += a1v * b1v; acc[1][2] += a1v * b2v; acc[1][3] += a1v * b3v;
        acc[2][0] += a2v * b0; acc[2][1] += a2v * b1v; acc[2][2] += a2v * b2v; acc[2][3] += a2v * b3v;
        acc[3][0] += a3v * b0; acc[3][1] += a3v * b1v; acc[3][2] += a3v * b2v; acc[3][3] += a3v * b3v;
      }
      #pragma unroll
      for (int i = 0; i < 4; i++)
        if (x0 + i < 49)
          #pragma unroll
          for (int j = 0; j < 4; j++)
            if (y0 + j < 49) u.a.A1[x0 + i][y0 + j] = acc[i][j] * scale;
    }
    __syncthreads();

    // ---- softmax stats: cols (a1, over x) and rows (a2, over y)
    if (tid < 98) {
      int isRow = tid >= 49;
      int j = tid - (isRow ? 49 : 0);
      float m = -1e30f;
      for (int k = 0; k < 49; k++) {
        float v = isRow ? u.a.A1[j][k] : u.a.A1[k][j];
        m = fmaxf(m, v);
      }
      float sm = 0.f;
      for (int k = 0; k < 49; k++) {
        float v = isRow ? u.a.A1[j][k] : u.a.A1[k][j];
        sm += __expf(v - m);
      }
      if (isRow) { rmax[j] = m; rsum[j] = 1.0f / sm; }
      else       { cmax[j] = m; csum[j] = 1.0f / sm; }
    }
    __syncthreads();

    // ---- A2 = softmax rows, A1 = softmax cols (in place)
    for (int i = tid; i < 49 * 49; i += 256) {
      int x = i / 49, y = i - x * 49;
      float v = u.a.A1[x][y];
      u.a.A2[x][y] = __expf(v - rmax[x]) * rsum[x];
      u.a.A1[x][y] = __expf(v - cmax[y]) * csum[y];
    }
    __syncthreads();

    // ---- o1[d][y] = sum_x A1[x][y]*V1[n*16+d][x];
    //      o2[d][x] = sum_y A2[x][y]*V2[n*16+d][y];  4d x 4t tiles, scatter out
    for (int task = tid; task < 2 * 4 * 13; task += 256) {
      int which = task / 52;
      int r = task - which * 52;
      int dg = r / 13, tg = r % 13;
      int d0 = dg * 4, t0 = tg * 4;
      int tc[4];
      #pragma unroll
      for (int j = 0; j < 4; j++) tc[j] = min(t0 + j, 48);
      float acc[4][4];
      #pragma unroll
      for (int i = 0; i < 4; i++)
        #pragma unroll
        for (int j = 0; j < 4; j++) acc[i][j] = 0.f;
      if (which == 0) {
        for (int x = 0; x < 49; x++) {
          float a0 = u.a.A1[x][tc[0]], a1v = u.a.A1[x][tc[1]];
          float a2v = u.a.A1[x][tc[2]], a3v = u.a.A1[x][tc[3]];
          #pragma unroll
          for (int i = 0; i < 4; i++) {
            float vv = kv[128 + n * HDV + d0 + i][x];
            acc[i][0] += vv * a0; acc[i][1] += vv * a1v;
            acc[i][2] += vv * a2v; acc[i][3] += vv * a3v;
          }
        }
      } else {
        for (int y = 0; y < 49; y++) {
          float a0 = u.a.A2[tc[0]][y], a1v = u.a.A2[tc[1]][y];
          float a2v = u.a.A2[tc[2]][y], a3v = u.a.A2[tc[3]][y];
          #pragma unroll
          for (int i = 0; i < 4; i++) {
            float vv = kv[160 + n * HDV + d0 + i][y];
            acc[i][0] += vv * a0; acc[i][1] += vv * a1v;
            acc[i][2] += vv * a2v; acc[i][3] += vv * a3v;
          }
        }
      }
      #pragma unroll
      for (int i = 0; i < 4; i++) {
        int ch = which * 32 + n * HDV + d0 + i;
        #pragma unroll
        for (int j = 0; j < 4; j++) {
          int t = t0 + j;
          if (t < 49) {
            int ph = t / 7, pw = t - ph * 7;
            OS[(((size_t)b * 64 + ch) * NS + (pi * 7 + ph)) * NS + (pj * 7 + pw)] = acc[i][j];
          }
        }
      }
    }
    __syncthreads();  // before next head reuses A1/A2
  }
}

// ---------------------------------------------------------------------------
// Kernel 2: one block per (b, h) output row. Unsampled rows: fill bp.
// Sampled rows: 64x64 projection of OS column for the 84 sampled w's, then
// fully coalesced row write selecting projected value or bp.
// ---------------------------------------------------------------------------
__global__ __launch_bounds__(256) void k2_outproj(
    const float* __restrict__ OS, const float* __restrict__ Wp,
    const float* __restrict__ bp, float* __restrict__ out)
{
  __shared__ float bps[64];
  __shared__ float os[64][85];
  __shared__ float res[64][85];
  __shared__ float wp[64][64];
  __shared__ int wsmap[256];

  const int tid = threadIdx.x;
  const int blk = blockIdx.x;
  const int b = blk / HH, h = blk % HH;

  if (tid < 64) bps[tid] = bp[tid];

  // map h -> sampled index hs (or -1): h = pi*21 + ph*4, ph in [0,6]
  int hs = -1;
  for (int pi = 0; pi < NPW; pi++) {
    int r = h - pi * STRIDE;
    if (r >= 0 && r <= (PDIM - 1) * DIL && (r % DIL) == 0) { hs = pi * PDIM + r / DIL; break; }
  }

  if (hs < 0) {
    __syncthreads();
    #pragma unroll 4
    for (int oc = 0; oc < 64; oc++)
      out[(((size_t)b * 64 + oc) * HH + h) * HH + tid] = bps[oc];
    return;
  }

  // map each w (=lane) -> ws or -1
  {
    int w = tid, wsv = -1;
    for (int pj = 0; pj < NPW; pj++) {
      int r = w - pj * STRIDE;
      if (r >= 0 && r <= (PDIM - 1) * DIL && (r % DIL) == 0) { wsv = pj * PDIM + r / DIL; break; }
    }
    wsmap[tid] = wsv;
  }
  for (int i = tid; i < 64 * 64; i += 256) wp[i / 64][i % 64] = Wp[i];
  for (int i = tid; i < 64 * NS; i += 256) {
    int c = i / NS, ws = i - c * NS;
    os[c][ws] = OS[(((size_t)b * 64 + c) * NS + hs) * NS + ws];
  }
  __syncthreads();

  for (int i = tid; i < 64 * NS; i += 256) {
    int oc = i / NS, ws = i - oc * NS;
    float acc = bps[oc];
    #pragma unroll
    for (int c = 0; c < 64; c++) acc += wp[oc][c] * os[c][ws];
    res[oc][ws] = acc;
  }
  __syncthreads();

  int wsv = wsmap[tid];
  #pragma unroll 4
  for (int oc = 0; oc < 64; oc++) {
    float v = (wsv >= 0) ? res[oc][wsv] : bps[oc];
    out[(((size_t)b * 64 + oc) * HH + h) * HH + tid] = v;
  }
}

extern "C" void kernel_launch(void* const* d_in, const int* in_sizes, int n_in,
                              void* d_out, int out_size, void* d_ws, size_t ws_size,
                              hipStream_t stream) {
  const float* x1 = (const float*)d_in[0];
  const float* x2 = (const float*)d_in[1];
  const float* Wk = (const float*)d_in[2];
  const float* bk = (const float*)d_in[3];
  const float* Wv = (const float*)d_in[4];
  const float* bv = (const float*)d_in[5];
  const float* Wp = (const float*)d_in[6];
  const float* bp = (const float*)d_in[7];
  float* OS = (float*)d_ws;  // 8*64*84*84 floats = 14.45 MB
  float* out = (float*)d_out;

  k1_fused<<<dim3(BB * SPP), dim3(256), 0, stream>>>(x1, x2, Wk, bk, Wv, bv, OS);
  k2_outproj<<<dim3(BB * HH), dim3(256), 0, stream>>>(OS, Wp, bp, out);
}